// Round 10
// baseline (1623.520 us; speedup 1.0000x reference)
//
#include <hip/hip_runtime.h>
#include <math.h>

#define FEAT 2048
#define HD 1024
#define FH 4096
#define NN 8192

using s16x8 = __attribute__((ext_vector_type(8))) short;
using f32x4 = __attribute__((ext_vector_type(4))) float;

#define GLOBAL_AS __attribute__((address_space(1)))
#define LDS_AS __attribute__((address_space(3)))

__device__ __forceinline__ void gload_lds16(const void* g, void* l) {
    __builtin_amdgcn_global_load_lds((const GLOBAL_AS unsigned int*)g,
                                     (LDS_AS unsigned int*)l, 16, 0, 0);
}

__device__ __forceinline__ unsigned short f2bf(float f) {
    union { float f; unsigned u; } v; v.f = f;
    unsigned r = v.u + 0x7FFFu + ((v.u >> 16) & 1u);  // RNE
    return (unsigned short)(r >> 16);
}

__device__ __forceinline__ float fast_sig(float x) { return 1.0f / (1.0f + __expf(-x)); }
__device__ __forceinline__ float fast_tanh(float x) {
    float ax = fabsf(x);
    float e = __expf(2.0f * ax);
    float r = 1.0f - 2.0f / (e + 1.0f);
    return copysignf(r, x);
}

// ---------------------------------------------------------------------------
// fused fp32 -> bf16 convert for feat, Wx, Wh
// ---------------------------------------------------------------------------
__global__ __launch_bounds__(256) void convert_all_kernel(
    const float* __restrict__ feat, const float* __restrict__ Wx,
    const float* __restrict__ Wh, unsigned short* __restrict__ feat_b,
    unsigned short* __restrict__ Wx_b, unsigned short* __restrict__ Wh_b)
{
    const size_t n1 = (size_t)NN * FEAT;
    const size_t n2 = n1 + (size_t)FH * FEAT;
    size_t i = ((size_t)blockIdx.x * 256 + threadIdx.x) * 8;
    const float* s; unsigned short* d;
    if (i < n1)      { s = feat + i;        d = feat_b + i; }
    else if (i < n2) { s = Wx + (i - n1);   d = Wx_b + (i - n1); }
    else             { s = Wh + (i - n2);   d = Wh_b + (i - n2); }
    float4 a = *(const float4*)s;
    float4 b = *(const float4*)(s + 4);
    unsigned short r[8] = {f2bf(a.x), f2bf(a.y), f2bf(a.z), f2bf(a.w),
                           f2bf(b.x), f2bf(b.y), f2bf(b.z), f2bf(b.w)};
    *(s16x8*)d = *(const s16x8*)r;
}

__global__ __launch_bounds__(256) void init_kernel(
    const float* __restrict__ root_h, const float* __restrict__ root_c,
    unsigned short* __restrict__ h_buf, float* __restrict__ c_buf)
{
    const int i = blockIdx.x * 256 + threadIdx.x;
    if (i < HD) { h_buf[i] = f2bf(root_h[i]); c_buf[i] = root_c[i]; }
}

// ---------------------------------------------------------------------------
// xproj = feat @ Wx^T + (bx+bh). 256x256 tile, BK=32, 64 KB LDS -> 2 blk/CU.
// Row-pair packed LDS: macro-row R (128 B) holds node rows 2R,2R+1; slot
// s = ((chunk ^ (R&3))<<1) | (row&1). Staged via pre-permuted per-lane global
// source (rule #21); read side uses the same involution -> 2-way max (free).
// ---------------------------------------------------------------------------
__global__ __launch_bounds__(512, 4) void xproj_8ph(
    const unsigned short* __restrict__ Ab,
    const unsigned short* __restrict__ Bb,
    const float* __restrict__ bx, const float* __restrict__ bh,
    float* __restrict__ xproj)
{
    __shared__ char lds[65536];
    const int tid = threadIdx.x;
    const int wid = tid >> 6;
    const int lane = tid & 63;
    const int wr = wid >> 2;
    const int wc = wid & 3;
    const int bm = blockIdx.x * 256;
    const int bn = blockIdx.y * 256;
    const int fr = lane & 15;
    const int fq = lane >> 4;

    // staging: issue q: macro R = q*64 + (tid>>3), slot ss = tid&7
    const int sR = tid >> 3;
    const int ss = tid & 7;
    const unsigned short* gA[2];
    const unsigned short* gB[2];
    #pragma unroll
    for (int q = 0; q < 2; ++q) {
        const int R = q * 64 + sR;
        const int node = 2 * R + (ss & 1);
        const int ck = (ss >> 1) ^ (R & 3);
        gA[q] = Ab + (size_t)(bm + node) * FEAT + ck * 8;
        gB[q] = Bb + (size_t)(bn + node) * FEAT + ck * 8;
    }
    const int ldsoff = tid * 16;

    f32x4 acc[8][4];
    #pragma unroll
    for (int i = 0; i < 8; ++i)
        #pragma unroll
        for (int j = 0; j < 4; ++j) { f32x4 z = {0.f, 0.f, 0.f, 0.f}; acc[i][j] = z; }

    // prologue: stage tile 0 into buf 0 (A at [0,16K), B at [16K,32K))
    #pragma unroll
    for (int q = 0; q < 2; ++q) {
        gload_lds16(gA[q], lds + q * 8192 + ldsoff);
        gload_lds16(gB[q], lds + 16384 + q * 8192 + ldsoff);
    }

    for (int t = 0; t < 64; ++t) {
        const char* LA = lds + (t & 1) * 32768;
        const char* LB = LA + 16384;
        char* SA = lds + ((t & 1) ^ 1) * 32768;
        char* SB = SA + 16384;
        const int knext = (t + 1) * 32;

        asm volatile("s_waitcnt vmcnt(0)" ::: "memory");
        __builtin_amdgcn_s_barrier();

        s16x8 aF[8], bF[4];
        #pragma unroll
        for (int i = 0; i < 8; ++i) {
            const int r = wr * 128 + i * 16 + fr;
            const int R = r >> 1;
            const int s = ((fq ^ (R & 3)) << 1) | (r & 1);
            aF[i] = *(const s16x8*)(LA + R * 128 + s * 16);
        }
        #pragma unroll
        for (int j = 0; j < 4; ++j) {
            const int r = wc * 64 + j * 16 + fr;
            const int R = r >> 1;
            const int s = ((fq ^ (R & 3)) << 1) | (r & 1);
            bF[j] = *(const s16x8*)(LB + R * 128 + s * 16);
        }
        if (t < 63) {
            #pragma unroll
            for (int q = 0; q < 2; ++q) {
                gload_lds16(gA[q] + knext, SA + q * 8192 + ldsoff);
                gload_lds16(gB[q] + knext, SB + q * 8192 + ldsoff);
            }
        }
        __builtin_amdgcn_s_setprio(1);
        #pragma unroll
        for (int i = 0; i < 8; ++i)
            #pragma unroll
            for (int j = 0; j < 4; ++j)
                acc[i][j] = __builtin_amdgcn_mfma_f32_16x16x32_bf16(
                    aF[i], bF[j], acc[i][j], 0, 0, 0);
        __builtin_amdgcn_s_setprio(0);
    }

    #pragma unroll
    for (int j = 0; j < 4; ++j) {
        const int col = bn + wc * 64 + j * 16 + fr;
        const float bias = bx[col] + bh[col];
        #pragma unroll
        for (int i = 0; i < 8; ++i) {
            const int rowb = bm + wr * 128 + i * 16 + fq * 4;
            #pragma unroll
            for (int reg = 0; reg < 4; ++reg)
                xproj[(size_t)(rowb + reg) * FH + col] = acc[i][j][reg] + bias;
        }
    }
}

// ---------------------------------------------------------------------------
// Large levels, gather-free, BK=32, row-pair packed LDS, 2 blocks/CU.
// Parents contiguous: node t = start + r has parent prevstart + (r>>1); the
// two rows of a macro-row share one parent (even/odd children). B mapping:
// tile row r -> Wh row ((r>>4)&3)*1024 + jg0 + (r>>6)*16 + (r&15): wave wc's
// fragment j = gate j at cols jg0+wc*16+[0,16) -> gates in-register.
// Grids: all (32,16) = 512 blocks (BM = count/32).
// ---------------------------------------------------------------------------
template<int BM>
__global__ __launch_bounds__(512, 4) void level_kk(
    const float* __restrict__ xproj, const unsigned short* __restrict__ Whb,
    int start, int prevstart, unsigned short* __restrict__ h_buf,
    float* __restrict__ c_buf, float* __restrict__ out)
{
    constexpr int MR = BM / 32;              // A frags per wave
    constexpr int ABYTES = BM * 64;          // BM/2 macro-rows x 128 B
    constexpr int BUF = ABYTES + 16384;      // + B (128 macros x 128 B)
    __shared__ char lds[2 * BUF];
    const int tid = threadIdx.x;
    const int wid = tid >> 6, lane = tid & 63;
    const int wr = wid >> 2, wc = wid & 3;
    const int fr = lane & 15, fq = lane >> 4;
    const int t0 = start + blockIdx.x * BM;
    const int jg0 = blockIdx.y * 64;

    const int sR = tid >> 3;
    const int ss = tid & 7;
    // A: one (masked) issue; macro R = sR < BM/2; both rows share the parent
    const bool aAct = (tid < BM * 4);
    const unsigned short* gA0 = h_buf +
        (size_t)(prevstart + blockIdx.x * (BM / 2) + sR + 1) * HD +
        ((ss >> 1) ^ (sR & 3)) * 8;
    // B: two issues
    const unsigned short* gB[2];
    #pragma unroll
    for (int q = 0; q < 2; ++q) {
        const int R = q * 64 + sR;
        const int br = 2 * R + (ss & 1);
        const int whrow = ((br >> 4) & 3) * 1024 + jg0 + ((br >> 6) * 16) + (br & 15);
        gB[q] = Whb + (size_t)whrow * HD + ((ss >> 1) ^ (R & 3)) * 8;
    }
    const int ldsoff = tid * 16;

    f32x4 acc[MR][4];
    #pragma unroll
    for (int i = 0; i < MR; ++i)
        #pragma unroll
        for (int j = 0; j < 4; ++j) { f32x4 z = {0.f, 0.f, 0.f, 0.f}; acc[i][j] = z; }

    if (aAct) gload_lds16(gA0, lds + ldsoff);
    #pragma unroll
    for (int q = 0; q < 2; ++q)
        gload_lds16(gB[q], lds + ABYTES + q * 8192 + ldsoff);

    for (int t = 0; t < 32; ++t) {
        const char* LA = lds + (t & 1) * BUF;
        const char* LB = LA + ABYTES;
        char* SA = lds + ((t & 1) ^ 1) * BUF;
        char* SB = SA + ABYTES;
        const int knext = (t + 1) * 32;

        asm volatile("s_waitcnt vmcnt(0)" ::: "memory");
        __builtin_amdgcn_s_barrier();

        s16x8 aF[MR], bF[4];
        #pragma unroll
        for (int i = 0; i < MR; ++i) {
            const int r = wr * (BM / 2) + i * 16 + fr;
            const int R = r >> 1;
            const int s = ((fq ^ (R & 3)) << 1) | (r & 1);
            aF[i] = *(const s16x8*)(LA + R * 128 + s * 16);
        }
        #pragma unroll
        for (int j = 0; j < 4; ++j) {
            const int r = wc * 64 + j * 16 + fr;
            const int R = r >> 1;
            const int s = ((fq ^ (R & 3)) << 1) | (r & 1);
            bF[j] = *(const s16x8*)(LB + R * 128 + s * 16);
        }
        if (t < 31) {
            if (aAct) gload_lds16(gA0 + knext, SA + ldsoff);
            #pragma unroll
            for (int q = 0; q < 2; ++q)
                gload_lds16(gB[q] + knext, SB + q * 8192 + ldsoff);
        }
        __builtin_amdgcn_s_setprio(1);
        #pragma unroll
        for (int i = 0; i < MR; ++i)
            #pragma unroll
            for (int j = 0; j < 4; ++j)
                acc[i][j] = __builtin_amdgcn_mfma_f32_16x16x32_bf16(
                    aF[i], bF[j], acc[i][j], 0, 0, 0);
        __builtin_amdgcn_s_setprio(0);
    }

    // epilogue: acc[i][g] = gate g at col jg0+wc*16+fr
    const int col = jg0 + wc * 16 + fr;
    #pragma unroll
    for (int i = 0; i < MR; ++i) {
        #pragma unroll
        for (int reg = 0; reg < 4; ++reg) {
            const int t = t0 + wr * (BM / 2) + i * 16 + fq * 4 + reg;
            const int p = (t - 1) >> 1;
            const size_t xb = (size_t)t * FH + col;
            const float gi = acc[i][0][reg] + xproj[xb];
            const float go = acc[i][1][reg] + xproj[xb + HD];
            const float gf = acc[i][2][reg] + xproj[xb + 2 * HD];
            const float gu = acc[i][3][reg] + xproj[xb + 3 * HD];
            const float cp = c_buf[(size_t)(p + 1) * HD + col];
            const float c = fast_sig(gi) * fast_tanh(gu) + fast_sig(gf) * cp;
            const float h = fast_sig(go) * fast_tanh(c);
            c_buf[(size_t)(t + 1) * HD + col] = c;
            h_buf[(size_t)(t + 1) * HD + col] = f2bf(h);
            out[(size_t)t * HD + col] = h;
        }
    }
}

// ---------------------------------------------------------------------------
// Shared gate epilogue (small levels, parent[] gather path)
// ---------------------------------------------------------------------------
__device__ __forceinline__ void level_epilogue(
    f32x4 (&acc)[4][4], const float* __restrict__ xproj,
    const int* __restrict__ parent, unsigned short* __restrict__ h_buf,
    float* __restrict__ c_buf, float* __restrict__ out,
    int t0, int lim, int wm, int col, int fq)
{
    #pragma unroll
    for (int i = 0; i < 4; ++i) {
        #pragma unroll
        for (int reg = 0; reg < 4; ++reg) {
            const int t = t0 + wm + i * 16 + fq * 4 + reg;
            if (t < lim) {
                const int p = parent[t];
                const size_t xb = (size_t)t * FH + col;
                const float gi = acc[i][0][reg] + xproj[xb];
                const float go = acc[i][1][reg] + xproj[xb + HD];
                const float gf = acc[i][2][reg] + xproj[xb + 2 * HD];
                const float gu = acc[i][3][reg] + xproj[xb + 3 * HD];
                const float cp = c_buf[(size_t)(p + 1) * HD + col];
                const float c = fast_sig(gi) * fast_tanh(gu) + fast_sig(gf) * cp;
                const float h = fast_sig(go) * fast_tanh(c);
                c_buf[(size_t)(t + 1) * HD + col] = c;
                h_buf[(size_t)(t + 1) * HD + col] = f2bf(h);
                out[(size_t)t * HD + col] = h;
            }
        }
    }
}

// ---------------------------------------------------------------------------
// BK=128 helpers (small levels)
// ---------------------------------------------------------------------------
__device__ __forceinline__ void bk128_issue(
    const unsigned short* const (&gA)[8], const unsigned short* const (&gB)[8],
    int k0, unsigned short* As, unsigned short* Bs, int wbase)
{
    #pragma unroll
    for (int q = 0; q < 8; ++q) {
        gload_lds16(gA[q] + k0, (char*)As + q * 4096 + wbase);
        gload_lds16(gB[q] + k0, (char*)Bs + q * 4096 + wbase);
    }
}

__device__ __forceinline__ void bk128_compute(
    const unsigned short* As, const unsigned short* Bs,
    f32x4 (&acc)[4][4], int wm, int wn16, int fr, int fkb)
{
    #pragma unroll
    for (int kk = 0; kk < 4; ++kk) {
        s16x8 aF[4], bF[4];
        #pragma unroll
        for (int i = 0; i < 4; ++i) {
            const int r = wm + i * 16 + fr;
            const int byteIn = (kk * 64 + fkb) ^ ((r & 7) << 4);
            aF[i] = *(const s16x8*)((const char*)As + r * 256 + byteIn);
        }
        #pragma unroll
        for (int g = 0; g < 4; ++g) {
            const int r = g * 32 + wn16 + fr;
            const int byteIn = (kk * 64 + fkb) ^ ((r & 7) << 4);
            bF[g] = *(const s16x8*)((const char*)Bs + r * 256 + byteIn);
        }
        #pragma unroll
        for (int i = 0; i < 4; ++i)
            #pragma unroll
            for (int g = 0; g < 4; ++g)
                acc[i][g] = __builtin_amdgcn_mfma_f32_16x16x32_bf16(aF[i], bF[g], acc[i][g], 0, 0, 0);
    }
}

// ---------------------------------------------------------------------------
// Small levels (count <= 512): BK=128 double-buffered (R5-proven)
// ---------------------------------------------------------------------------
__global__ __launch_bounds__(256) void level_bk128_dbuf(
    const float* __restrict__ xproj, const unsigned short* __restrict__ Whb,
    const int* __restrict__ parent, unsigned short* __restrict__ h_buf,
    float* __restrict__ c_buf, float* __restrict__ out,
    int start, int count)
{
    __shared__ unsigned short As0[128 * 128];
    __shared__ unsigned short Bs0[128 * 128];
    __shared__ unsigned short As1[128 * 128];
    __shared__ unsigned short Bs1[128 * 128];
    const int tid = threadIdx.x;
    const int wid = tid >> 6;
    const int lane = tid & 63;
    const int t0 = start + blockIdx.x * 128;
    const int jg0 = blockIdx.y * 32;
    const int lim = start + count;
    const int wm = (wid & 1) * 64;
    const int wn16 = (wid >> 1) * 16;
    const int wbase = wid * 1024;
    const int srow_b = tid >> 4;
    const int rowbyte = (tid & 15) * 16;

    const unsigned short* gA[8];
    const unsigned short* gB[8];
    #pragma unroll
    for (int q = 0; q < 8; ++q) {
        const int r = q * 16 + srow_b;
        const int sk = (rowbyte ^ ((r & 7) << 4)) >> 1;
        const int tA = min(t0 + r, lim - 1);
        gA[q] = h_buf + (size_t)(parent[tA] + 1) * HD + sk;
        const int whrow = ((r >> 5) << 10) + jg0 + (r & 31);
        gB[q] = Whb + (size_t)whrow * HD + sk;
    }

    f32x4 acc[4][4];
    #pragma unroll
    for (int i = 0; i < 4; ++i)
        #pragma unroll
        for (int g = 0; g < 4; ++g) { f32x4 z = {0.f, 0.f, 0.f, 0.f}; acc[i][g] = z; }

    const int fr = lane & 15;
    const int fkb = (lane >> 4) * 16;

    bk128_issue(gA, gB, 0, As0, Bs0, wbase);
    #pragma unroll
    for (int t = 0; t < 8; ++t) {
        unsigned short* curA = (t & 1) ? As1 : As0;
        unsigned short* curB = (t & 1) ? Bs1 : Bs0;
        unsigned short* nxtA = (t & 1) ? As0 : As1;
        unsigned short* nxtB = (t & 1) ? Bs0 : Bs1;
        if (t < 7) {
            bk128_issue(gA, gB, (t + 1) * 128, nxtA, nxtB, wbase);
            asm volatile("s_waitcnt vmcnt(16)" ::: "memory");
        } else {
            asm volatile("s_waitcnt vmcnt(0)" ::: "memory");
        }
        __builtin_amdgcn_s_barrier();
        __builtin_amdgcn_sched_barrier(0);
        bk128_compute(curA, curB, acc, wm, wn16, fr, fkb);
        __builtin_amdgcn_sched_barrier(0);
        __builtin_amdgcn_s_barrier();
    }

    level_epilogue(acc, xproj, parent, h_buf, c_buf, out,
                   t0, lim, wm, jg0 + wn16 + fr, lane >> 4);
}

extern "C" void kernel_launch(void* const* d_in, const int* in_sizes, int n_in,
                              void* d_out, int out_size, void* d_ws, size_t ws_size,
                              hipStream_t stream) {
    const float* feat   = (const float*)d_in[0];
    const float* Wx     = (const float*)d_in[1];
    const float* bx     = (const float*)d_in[2];
    const float* Wh     = (const float*)d_in[3];
    const float* bh     = (const float*)d_in[4];
    const int*   parent = (const int*)d_in[5];
    const float* root_c = (const float*)d_in[6];
    const float* root_h = (const float*)d_in[7];
    float* out = (float*)d_out;

    char* ws = (char*)d_ws;
    float* xproj = (float*)ws;                          ws += (size_t)NN * FH * 4;
    float* c_buf = (float*)ws;                          ws += (size_t)(NN + 1) * HD * 4;
    unsigned short* feat_b = (unsigned short*)ws;       ws += (size_t)NN * FEAT * 2;
    unsigned short* Wx_b = (unsigned short*)ws;         ws += (size_t)FH * FEAT * 2;
    unsigned short* Wh_b = (unsigned short*)ws;         ws += (size_t)FH * HD * 2;
    unsigned short* h_buf = (unsigned short*)ws;        ws += (size_t)(NN + 1) * HD * 2;

    const size_t ntot = (size_t)NN * FEAT + (size_t)FH * FEAT + (size_t)FH * HD;
    convert_all_kernel<<<(unsigned)(ntot / 8 / 256), 256, 0, stream>>>(
        feat, Wx, Wh, feat_b, Wx_b, Wh_b);
    init_kernel<<<4, 256, 0, stream>>>(root_h, root_c, h_buf, c_buf);

    dim3 g1(NN / 256, FH / 256);
    xproj_8ph<<<g1, 512, 0, stream>>>(feat_b, Wx_b, bx, bh, xproj);

    // small levels (counts 1..512), gathered via parent[]
    for (int start = 0, sz = 1; sz <= 512; start += sz, sz *= 2) {
        dim3 g2((sz + 127) / 128, HD / 32);
        level_bk128_dbuf<<<g2, 256, 0, stream>>>(
            xproj, Wh_b, parent, h_buf, c_buf, out, start, sz);
    }

    // large levels: gather-free kk-split, 512 blocks each (2 blocks/CU)
    dim3 gl(32, 16);
    level_kk<32><<<gl, 512, 0, stream>>>(xproj, Wh_b, 1023, 511,
                                         h_buf, c_buf, out);
    level_kk<64><<<gl, 512, 0, stream>>>(xproj, Wh_b, 2047, 1023,
                                         h_buf, c_buf, out);
    level_kk<128><<<gl, 512, 0, stream>>>(xproj, Wh_b, 4095, 2047,
                                          h_buf, c_buf, out);

    // straggler node 8191 (parent 4095 via h_buf/c_buf)
    dim3 g3(1, HD / 32);
    level_bk128_dbuf<<<g3, 256, 0, stream>>>(
        xproj, Wh_b, parent, h_buf, c_buf, out, 8191, 1);
}

// Round 11
// 469.328 us; speedup vs baseline: 3.4592x; 3.4592x over previous
//
#include <hip/hip_runtime.h>
#include <math.h>

#define FEAT 2048
#define HD 1024
#define FH 4096
#define NN 8192

using s16x8 = __attribute__((ext_vector_type(8))) short;
using f32x4 = __attribute__((ext_vector_type(4))) float;

#define GLOBAL_AS __attribute__((address_space(1)))
#define LDS_AS __attribute__((address_space(3)))

__device__ __forceinline__ void gload_lds16(const void* g, void* l) {
    __builtin_amdgcn_global_load_lds((const GLOBAL_AS unsigned int*)g,
                                     (LDS_AS unsigned int*)l, 16, 0, 0);
}

__device__ __forceinline__ unsigned short f2bf(float f) {
    union { float f; unsigned u; } v; v.f = f;
    unsigned r = v.u + 0x7FFFu + ((v.u >> 16) & 1u);  // RNE
    return (unsigned short)(r >> 16);
}

__device__ __forceinline__ float fast_sig(float x) { return 1.0f / (1.0f + __expf(-x)); }
__device__ __forceinline__ float fast_tanh(float x) {
    float ax = fabsf(x);
    float e = __expf(2.0f * ax);
    float r = 1.0f - 2.0f / (e + 1.0f);
    return copysignf(r, x);
}

// ---------------------------------------------------------------------------
// fused fp32 -> bf16 convert for feat, Wx, Wh
// ---------------------------------------------------------------------------
__global__ __launch_bounds__(256) void convert_all_kernel(
    const float* __restrict__ feat, const float* __restrict__ Wx,
    const float* __restrict__ Wh, unsigned short* __restrict__ feat_b,
    unsigned short* __restrict__ Wx_b, unsigned short* __restrict__ Wh_b)
{
    const size_t n1 = (size_t)NN * FEAT;
    const size_t n2 = n1 + (size_t)FH * FEAT;
    size_t i = ((size_t)blockIdx.x * 256 + threadIdx.x) * 8;
    const float* s; unsigned short* d;
    if (i < n1)      { s = feat + i;        d = feat_b + i; }
    else if (i < n2) { s = Wx + (i - n1);   d = Wx_b + (i - n1); }
    else             { s = Wh + (i - n2);   d = Wh_b + (i - n2); }
    float4 a = *(const float4*)s;
    float4 b = *(const float4*)(s + 4);
    unsigned short r[8] = {f2bf(a.x), f2bf(a.y), f2bf(a.z), f2bf(a.w),
                           f2bf(b.x), f2bf(b.y), f2bf(b.z), f2bf(b.w)};
    *(s16x8*)d = *(const s16x8*)r;
}

__global__ __launch_bounds__(256) void init_kernel(
    const float* __restrict__ root_h, const float* __restrict__ root_c,
    unsigned short* __restrict__ h_buf, float* __restrict__ c_buf)
{
    const int i = blockIdx.x * 256 + threadIdx.x;
    if (i < HD) { h_buf[i] = f2bf(root_h[i]); c_buf[i] = root_c[i]; }
}

// ---------------------------------------------------------------------------
// xproj = feat @ Wx^T + (bx+bh). 256x256 tile, BK=32, 3-BUFFER pipeline:
// stage tile t+2 while computing t; counted s_waitcnt vmcnt(4) (tile t's 4
// loads are always the oldest outstanding) — vmcnt(0) only on the last tile.
// Row-pair packed LDS (R10-verified, 0 conflicts): macro-row R (128 B) holds
// node rows 2R,2R+1; slot s = ((chunk ^ (R&3))<<1) | (row&1); staged via
// pre-permuted per-lane global source (rule #21 both-sides).
// launch_bounds (512,2): 256-reg budget — R10 showed (512,4) spills acc.
// ---------------------------------------------------------------------------
__global__ __launch_bounds__(512, 2) void xproj_8ph(
    const unsigned short* __restrict__ Ab,
    const unsigned short* __restrict__ Bb,
    const float* __restrict__ bx, const float* __restrict__ bh,
    float* __restrict__ xproj)
{
    __shared__ char lds[98304];              // 3 x (A 16K + B 16K)
    const int tid = threadIdx.x;
    const int wid = tid >> 6;
    const int lane = tid & 63;
    const int wr = wid >> 2;
    const int wc = wid & 3;
    const int bm = blockIdx.x * 256;
    const int bn = blockIdx.y * 256;
    const int fr = lane & 15;
    const int fq = lane >> 4;

    // staging: issue q: macro R = q*64 + (tid>>3), slot ss = tid&7
    const int sR = tid >> 3;
    const int ss = tid & 7;
    const unsigned short* gA[2];
    const unsigned short* gB[2];
    #pragma unroll
    for (int q = 0; q < 2; ++q) {
        const int R = q * 64 + sR;
        const int node = 2 * R + (ss & 1);
        const int ck = (ss >> 1) ^ (R & 3);
        gA[q] = Ab + (size_t)(bm + node) * FEAT + ck * 8;
        gB[q] = Bb + (size_t)(bn + node) * FEAT + ck * 8;
    }
    const int ldsoff = tid * 16;

    f32x4 acc[8][4];
    #pragma unroll
    for (int i = 0; i < 8; ++i)
        #pragma unroll
        for (int j = 0; j < 4; ++j) { f32x4 z = {0.f, 0.f, 0.f, 0.f}; acc[i][j] = z; }

    // prologue: stage tiles 0,1 into bufs 0,1 (4 loads each)
    #pragma unroll
    for (int t = 0; t < 2; ++t) {
        char* S = lds + t * 32768;
        #pragma unroll
        for (int q = 0; q < 2; ++q) {
            gload_lds16(gA[q] + t * 32, S + q * 8192 + ldsoff);
            gload_lds16(gB[q] + t * 32, S + 16384 + q * 8192 + ldsoff);
        }
    }

    int cur = 0;
    for (int t = 0; t < 64; ++t) {
        const char* LA = lds + cur * 32768;
        const char* LB = LA + 16384;

        // complete tile t's 4 loads (oldest); keep t+1's in flight
        if (t < 63) { asm volatile("s_waitcnt vmcnt(4)" ::: "memory"); }
        else        { asm volatile("s_waitcnt vmcnt(0)" ::: "memory"); }
        __builtin_amdgcn_s_barrier();   // all waves done reading buf (t-1)%3

        // stage tile t+2 into buf (t+2)%3 (the one just freed)
        if (t < 62) {
            char* S = lds + ((cur + 2) % 3) * 32768;
            const int knext = (t + 2) * 32;
            #pragma unroll
            for (int q = 0; q < 2; ++q) {
                gload_lds16(gA[q] + knext, S + q * 8192 + ldsoff);
                gload_lds16(gB[q] + knext, S + 16384 + q * 8192 + ldsoff);
            }
        }

        s16x8 aF[8], bF[4];
        #pragma unroll
        for (int i = 0; i < 8; ++i) {
            const int r = wr * 128 + i * 16 + fr;
            const int R = r >> 1;
            const int s = ((fq ^ (R & 3)) << 1) | (r & 1);
            aF[i] = *(const s16x8*)(LA + R * 128 + s * 16);
        }
        #pragma unroll
        for (int j = 0; j < 4; ++j) {
            const int r = wc * 64 + j * 16 + fr;
            const int R = r >> 1;
            const int s = ((fq ^ (R & 3)) << 1) | (r & 1);
            bF[j] = *(const s16x8*)(LB + R * 128 + s * 16);
        }
        __builtin_amdgcn_s_setprio(1);
        #pragma unroll
        for (int i = 0; i < 8; ++i)
            #pragma unroll
            for (int j = 0; j < 4; ++j)
                acc[i][j] = __builtin_amdgcn_mfma_f32_16x16x32_bf16(
                    aF[i], bF[j], acc[i][j], 0, 0, 0);
        __builtin_amdgcn_s_setprio(0);

        cur = (cur + 1) % 3;
    }

    #pragma unroll
    for (int j = 0; j < 4; ++j) {
        const int col = bn + wc * 64 + j * 16 + fr;
        const float bias = bx[col] + bh[col];
        #pragma unroll
        for (int i = 0; i < 8; ++i) {
            const int rowb = bm + wr * 128 + i * 16 + fq * 4;
            #pragma unroll
            for (int reg = 0; reg < 4; ++reg)
                xproj[(size_t)(rowb + reg) * FH + col] = acc[i][j][reg] + bias;
        }
    }
}

// ---------------------------------------------------------------------------
// Large levels (R9-proven): gather-free, BK=64, 2-buffer. Parents contiguous:
// node t = start + r has parent prevstart + (r>>1). B: tile row r -> Wh row
// ((r>>4)&3)*1024 + jg0 + (r>>6)*16 + (r&15) -> gates in-register.
// ---------------------------------------------------------------------------
template<int BM>
__global__ __launch_bounds__(512, 2) void level_kk(
    const float* __restrict__ xproj, const unsigned short* __restrict__ Whb,
    int start, int prevstart, unsigned short* __restrict__ h_buf,
    float* __restrict__ c_buf, float* __restrict__ out)
{
    constexpr int MR = BM / 32;
    constexpr int ABYTES = BM * 128;
    constexpr int BUF = ABYTES + 32768;
    __shared__ char lds[2 * BUF];
    const int tid = threadIdx.x;
    const int wid = tid >> 6, lane = tid & 63;
    const int wr = wid >> 2, wc = wid & 3;
    const int fr = lane & 15, fq = lane >> 4;
    const int t0 = start + blockIdx.x * BM;
    const int jg0 = blockIdx.y * 64;

    const int srow = tid >> 3;
    const int sslot = (tid & 7) ^ (srow & 7);
    const unsigned short* gA[BM / 64];
    #pragma unroll
    for (int q = 0; q < BM / 64; ++q) {
        const int rg = blockIdx.x * BM + q * 64 + srow;
        gA[q] = h_buf + (size_t)(prevstart + (rg >> 1) + 1) * HD + sslot * 8;
    }
    const unsigned short* gB[4];
    #pragma unroll
    for (int q = 0; q < 4; ++q) {
        const int r = q * 64 + srow;
        const int whrow = ((r >> 4) & 3) * 1024 + jg0 + ((r >> 6) * 16) + (r & 15);
        gB[q] = Whb + (size_t)whrow * HD + sslot * 8;
    }
    const int ldsoff = tid * 16;

    f32x4 acc[MR][4];
    #pragma unroll
    for (int i = 0; i < MR; ++i)
        #pragma unroll
        for (int j = 0; j < 4; ++j) { f32x4 z = {0.f, 0.f, 0.f, 0.f}; acc[i][j] = z; }

    #pragma unroll
    for (int q = 0; q < BM / 64; ++q)
        gload_lds16(gA[q], lds + q * 8192 + ldsoff);
    #pragma unroll
    for (int q = 0; q < 4; ++q)
        gload_lds16(gB[q], lds + ABYTES + q * 8192 + ldsoff);

    for (int t = 0; t < 16; ++t) {
        const char* LA = lds + (t & 1) * BUF;
        const char* LB = LA + ABYTES;
        char* SA = lds + ((t & 1) ^ 1) * BUF;
        char* SB = SA + ABYTES;
        const int knext = (t + 1) * 64;

        asm volatile("s_waitcnt vmcnt(0)" ::: "memory");
        __builtin_amdgcn_s_barrier();

        #pragma unroll
        for (int kk = 0; kk < 2; ++kk) {
            const int kbyte = kk * 64 + fq * 16;
            s16x8 aF[MR], bF[4];
            #pragma unroll
            for (int i = 0; i < MR; ++i) {
                const int row = wr * (BM / 2) + i * 16 + fr;
                aF[i] = *(const s16x8*)(LA + row * 128 + (kbyte ^ ((row & 7) << 4)));
            }
            #pragma unroll
            for (int j = 0; j < 4; ++j) {
                const int row = wc * 64 + j * 16 + fr;
                bF[j] = *(const s16x8*)(LB + row * 128 + (kbyte ^ ((row & 7) << 4)));
            }
            if (t < 15) {
                if (kk == 0) {
                    #pragma unroll
                    for (int q = 0; q < BM / 64; ++q)
                        gload_lds16(gA[q] + knext, SA + q * 8192 + ldsoff);
                } else {
                    #pragma unroll
                    for (int q = 0; q < 4; ++q)
                        gload_lds16(gB[q] + knext, SB + q * 8192 + ldsoff);
                }
            }
            __builtin_amdgcn_s_setprio(1);
            #pragma unroll
            for (int i = 0; i < MR; ++i)
                #pragma unroll
                for (int j = 0; j < 4; ++j)
                    acc[i][j] = __builtin_amdgcn_mfma_f32_16x16x32_bf16(
                        aF[i], bF[j], acc[i][j], 0, 0, 0);
            __builtin_amdgcn_s_setprio(0);
        }
    }

    const int col = jg0 + wc * 16 + fr;
    #pragma unroll
    for (int i = 0; i < MR; ++i) {
        #pragma unroll
        for (int reg = 0; reg < 4; ++reg) {
            const int t = t0 + wr * (BM / 2) + i * 16 + fq * 4 + reg;
            const int p = (t - 1) >> 1;
            const size_t xb = (size_t)t * FH + col;
            const float gi = acc[i][0][reg] + xproj[xb];
            const float go = acc[i][1][reg] + xproj[xb + HD];
            const float gf = acc[i][2][reg] + xproj[xb + 2 * HD];
            const float gu = acc[i][3][reg] + xproj[xb + 3 * HD];
            const float cp = c_buf[(size_t)(p + 1) * HD + col];
            const float c = fast_sig(gi) * fast_tanh(gu) + fast_sig(gf) * cp;
            const float h = fast_sig(go) * fast_tanh(c);
            c_buf[(size_t)(t + 1) * HD + col] = c;
            h_buf[(size_t)(t + 1) * HD + col] = f2bf(h);
            out[(size_t)t * FH / 4 + col] = h;   // FH/4 == HD
        }
    }
}

// ---------------------------------------------------------------------------
// Shared gate epilogue (small levels, parent[] gather path)
// ---------------------------------------------------------------------------
__device__ __forceinline__ void level_epilogue(
    f32x4 (&acc)[4][4], const float* __restrict__ xproj,
    const int* __restrict__ parent, unsigned short* __restrict__ h_buf,
    float* __restrict__ c_buf, float* __restrict__ out,
    int t0, int lim, int wm, int col, int fq)
{
    #pragma unroll
    for (int i = 0; i < 4; ++i) {
        #pragma unroll
        for (int reg = 0; reg < 4; ++reg) {
            const int t = t0 + wm + i * 16 + fq * 4 + reg;
            if (t < lim) {
                const int p = parent[t];
                const size_t xb = (size_t)t * FH + col;
                const float gi = acc[i][0][reg] + xproj[xb];
                const float go = acc[i][1][reg] + xproj[xb + HD];
                const float gf = acc[i][2][reg] + xproj[xb + 2 * HD];
                const float gu = acc[i][3][reg] + xproj[xb + 3 * HD];
                const float cp = c_buf[(size_t)(p + 1) * HD + col];
                const float c = fast_sig(gi) * fast_tanh(gu) + fast_sig(gf) * cp;
                const float h = fast_sig(go) * fast_tanh(c);
                c_buf[(size_t)(t + 1) * HD + col] = c;
                h_buf[(size_t)(t + 1) * HD + col] = f2bf(h);
                out[(size_t)t * HD + col] = h;
            }
        }
    }
}

// ---------------------------------------------------------------------------
// BK=128 helpers (small levels)
// ---------------------------------------------------------------------------
__device__ __forceinline__ void bk128_issue(
    const unsigned short* const (&gA)[8], const unsigned short* const (&gB)[8],
    int k0, unsigned short* As, unsigned short* Bs, int wbase)
{
    #pragma unroll
    for (int q = 0; q < 8; ++q) {
        gload_lds16(gA[q] + k0, (char*)As + q * 4096 + wbase);
        gload_lds16(gB[q] + k0, (char*)Bs + q * 4096 + wbase);
    }
}

__device__ __forceinline__ void bk128_compute(
    const unsigned short* As, const unsigned short* Bs,
    f32x4 (&acc)[4][4], int wm, int wn16, int fr, int fkb)
{
    #pragma unroll
    for (int kk = 0; kk < 4; ++kk) {
        s16x8 aF[4], bF[4];
        #pragma unroll
        for (int i = 0; i < 4; ++i) {
            const int r = wm + i * 16 + fr;
            const int byteIn = (kk * 64 + fkb) ^ ((r & 7) << 4);
            aF[i] = *(const s16x8*)((const char*)As + r * 256 + byteIn);
        }
        #pragma unroll
        for (int g = 0; g < 4; ++g) {
            const int r = g * 32 + wn16 + fr;
            const int byteIn = (kk * 64 + fkb) ^ ((r & 7) << 4);
            bF[g] = *(const s16x8*)((const char*)Bs + r * 256 + byteIn);
        }
        #pragma unroll
        for (int i = 0; i < 4; ++i)
            #pragma unroll
            for (int g = 0; g < 4; ++g)
                acc[i][g] = __builtin_amdgcn_mfma_f32_16x16x32_bf16(aF[i], bF[g], acc[i][g], 0, 0, 0);
    }
}

// ---------------------------------------------------------------------------
// Small levels (count <= 512): BK=128 double-buffered (R5-proven)
// ---------------------------------------------------------------------------
__global__ __launch_bounds__(256) void level_bk128_dbuf(
    const float* __restrict__ xproj, const unsigned short* __restrict__ Whb,
    const int* __restrict__ parent, unsigned short* __restrict__ h_buf,
    float* __restrict__ c_buf, float* __restrict__ out,
    int start, int count)
{
    __shared__ unsigned short As0[128 * 128];
    __shared__ unsigned short Bs0[128 * 128];
    __shared__ unsigned short As1[128 * 128];
    __shared__ unsigned short Bs1[128 * 128];
    const int tid = threadIdx.x;
    const int wid = tid >> 6;
    const int lane = tid & 63;
    const int t0 = start + blockIdx.x * 128;
    const int jg0 = blockIdx.y * 32;
    const int lim = start + count;
    const int wm = (wid & 1) * 64;
    const int wn16 = (wid >> 1) * 16;
    const int wbase = wid * 1024;
    const int srow_b = tid >> 4;
    const int rowbyte = (tid & 15) * 16;

    const unsigned short* gA[8];
    const unsigned short* gB[8];
    #pragma unroll
    for (int q = 0; q < 8; ++q) {
        const int r = q * 16 + srow_b;
        const int sk = (rowbyte ^ ((r & 7) << 4)) >> 1;
        const int tA = min(t0 + r, lim - 1);
        gA[q] = h_buf + (size_t)(parent[tA] + 1) * HD + sk;
        const int whrow = ((r >> 5) << 10) + jg0 + (r & 31);
        gB[q] = Whb + (size_t)whrow * HD + sk;
    }

    f32x4 acc[4][4];
    #pragma unroll
    for (int i = 0; i < 4; ++i)
        #pragma unroll
        for (int g = 0; g < 4; ++g) { f32x4 z = {0.f, 0.f, 0.f, 0.f}; acc[i][g] = z; }

    const int fr = lane & 15;
    const int fkb = (lane >> 4) * 16;

    bk128_issue(gA, gB, 0, As0, Bs0, wbase);
    #pragma unroll
    for (int t = 0; t < 8; ++t) {
        unsigned short* curA = (t & 1) ? As1 : As0;
        unsigned short* curB = (t & 1) ? Bs1 : Bs0;
        unsigned short* nxtA = (t & 1) ? As0 : As1;
        unsigned short* nxtB = (t & 1) ? Bs0 : Bs1;
        if (t < 7) {
            bk128_issue(gA, gB, (t + 1) * 128, nxtA, nxtB, wbase);
            asm volatile("s_waitcnt vmcnt(16)" ::: "memory");
        } else {
            asm volatile("s_waitcnt vmcnt(0)" ::: "memory");
        }
        __builtin_amdgcn_s_barrier();
        __builtin_amdgcn_sched_barrier(0);
        bk128_compute(curA, curB, acc, wm, wn16, fr, fkb);
        __builtin_amdgcn_sched_barrier(0);
        __builtin_amdgcn_s_barrier();
    }

    level_epilogue(acc, xproj, parent, h_buf, c_buf, out,
                   t0, lim, wm, jg0 + wn16 + fr, lane >> 4);
}

extern "C" void kernel_launch(void* const* d_in, const int* in_sizes, int n_in,
                              void* d_out, int out_size, void* d_ws, size_t ws_size,
                              hipStream_t stream) {
    const float* feat   = (const float*)d_in[0];
    const float* Wx     = (const float*)d_in[1];
    const float* bx     = (const float*)d_in[2];
    const float* Wh     = (const float*)d_in[3];
    const float* bh     = (const float*)d_in[4];
    const int*   parent = (const int*)d_in[5];
    const float* root_c = (const float*)d_in[6];
    const float* root_h = (const float*)d_in[7];
    float* out = (float*)d_out;

    char* ws = (char*)d_ws;
    float* xproj = (float*)ws;                          ws += (size_t)NN * FH * 4;
    float* c_buf = (float*)ws;                          ws += (size_t)(NN + 1) * HD * 4;
    unsigned short* feat_b = (unsigned short*)ws;       ws += (size_t)NN * FEAT * 2;
    unsigned short* Wx_b = (unsigned short*)ws;         ws += (size_t)FH * FEAT * 2;
    unsigned short* Wh_b = (unsigned short*)ws;         ws += (size_t)FH * HD * 2;
    unsigned short* h_buf = (unsigned short*)ws;        ws += (size_t)(NN + 1) * HD * 2;

    const size_t ntot = (size_t)NN * FEAT + (size_t)FH * FEAT + (size_t)FH * HD;
    convert_all_kernel<<<(unsigned)(ntot / 8 / 256), 256, 0, stream>>>(
        feat, Wx, Wh, feat_b, Wx_b, Wh_b);
    init_kernel<<<4, 256, 0, stream>>>(root_h, root_c, h_buf, c_buf);

    dim3 g1(NN / 256, FH / 256);
    xproj_8ph<<<g1, 512, 0, stream>>>(feat_b, Wx_b, bx, bh, xproj);

    // small levels (counts 1..512), gathered via parent[]
    for (int start = 0, sz = 1; sz <= 512; start += sz, sz *= 2) {
        dim3 g2((sz + 127) / 128, HD / 32);
        level_bk128_dbuf<<<g2, 256, 0, stream>>>(
            xproj, Wh_b, parent, h_buf, c_buf, out, start, sz);
    }

    // large levels: gather-free kk-split (R9-proven), 256 blocks each
    dim3 gl(16, 16);
    level_kk<64><<<gl, 512, 0, stream>>>(xproj, Wh_b, 1023, 511,
                                         h_buf, c_buf, out);
    level_kk<128><<<gl, 512, 0, stream>>>(xproj, Wh_b, 2047, 1023,
                                          h_buf, c_buf, out);
    level_kk<256><<<gl, 512, 0, stream>>>(xproj, Wh_b, 4095, 2047,
                                          h_buf, c_buf, out);

    // straggler node 8191 (parent 4095 via h_buf/c_buf)
    dim3 g3(1, HD / 32);
    level_bk128_dbuf<<<g3, 256, 0, stream>>>(
        xproj, Wh_b, parent, h_buf, c_buf, out, 8191, 1);
}

// Round 12
// 451.210 us; speedup vs baseline: 3.5982x; 1.0402x over previous
//
#include <hip/hip_runtime.h>
#include <hip/hip_fp16.h>
#include <math.h>

#define FEAT 2048
#define HD 1024
#define FH 4096
#define NN 8192

using s16x8 = __attribute__((ext_vector_type(8))) short;
using f32x4 = __attribute__((ext_vector_type(4))) float;

#define GLOBAL_AS __attribute__((address_space(1)))
#define LDS_AS __attribute__((address_space(3)))

__device__ __forceinline__ void gload_lds16(const void* g, void* l) {
    __builtin_amdgcn_global_load_lds((const GLOBAL_AS unsigned int*)g,
                                     (LDS_AS unsigned int*)l, 16, 0, 0);
}

__device__ __forceinline__ unsigned short f2bf(float f) {
    union { float f; unsigned u; } v; v.f = f;
    unsigned r = v.u + 0x7FFFu + ((v.u >> 16) & 1u);  // RNE
    return (unsigned short)(r >> 16);
}

__device__ __forceinline__ float fast_sig(float x) { return 1.0f / (1.0f + __expf(-x)); }
__device__ __forceinline__ float fast_tanh(float x) {
    float ax = fabsf(x);
    float e = __expf(2.0f * ax);
    float r = 1.0f - 2.0f / (e + 1.0f);
    return copysignf(r, x);
}

// ---------------------------------------------------------------------------
// fused fp32 -> bf16 convert for feat, Wx, Wh  (+ root h/c init, fused)
// ---------------------------------------------------------------------------
__global__ __launch_bounds__(256) void convert_all_kernel(
    const float* __restrict__ feat, const float* __restrict__ Wx,
    const float* __restrict__ Wh, unsigned short* __restrict__ feat_b,
    unsigned short* __restrict__ Wx_b, unsigned short* __restrict__ Wh_b,
    const float* __restrict__ root_h, const float* __restrict__ root_c,
    unsigned short* __restrict__ h_buf, float* __restrict__ c_buf)
{
    const size_t g = (size_t)blockIdx.x * 256 + threadIdx.x;
    if (g < HD) { h_buf[g] = f2bf(root_h[g]); c_buf[g] = root_c[g]; }

    const size_t n1 = (size_t)NN * FEAT;
    const size_t n2 = n1 + (size_t)FH * FEAT;
    size_t i = g * 8;
    const float* s; unsigned short* d;
    if (i < n1)      { s = feat + i;        d = feat_b + i; }
    else if (i < n2) { s = Wx + (i - n1);   d = Wx_b + (i - n1); }
    else             { s = Wh + (i - n2);   d = Wh_b + (i - n2); }
    float4 a = *(const float4*)s;
    float4 b = *(const float4*)(s + 4);
    unsigned short r[8] = {f2bf(a.x), f2bf(a.y), f2bf(a.z), f2bf(a.w),
                           f2bf(b.x), f2bf(b.y), f2bf(b.z), f2bf(b.w)};
    *(s16x8*)d = *(const s16x8*)r;
}

// ---------------------------------------------------------------------------
// xproj = feat @ Wx^T + (bx+bh). 256x256 BK=64 kk-split (R7-proven schedule;
// R10/R11 refuted higher-occupancy and 3-buffer variants). fp16 output.
// ---------------------------------------------------------------------------
__global__ __launch_bounds__(512, 2) void xproj_8ph(
    const unsigned short* __restrict__ Ab,
    const unsigned short* __restrict__ Bb,
    const float* __restrict__ bx, const float* __restrict__ bh,
    __half* __restrict__ xproj)
{
    __shared__ char lds[131072];
    const int tid = threadIdx.x;
    const int wid = tid >> 6;
    const int lane = tid & 63;
    const int wr = wid >> 2;
    const int wc = wid & 3;
    const int bm = blockIdx.x * 256;
    const int bn = blockIdx.y * 256;
    const int fr = lane & 15;
    const int fq = lane >> 4;

    const int srow = tid >> 3;
    const int sslot = (tid & 7) ^ (srow & 7);
    const unsigned short* gA[4];
    const unsigned short* gB[4];
    #pragma unroll
    for (int q = 0; q < 4; ++q) {
        gA[q] = Ab + (size_t)(bm + q * 64 + srow) * FEAT + sslot * 8;
        gB[q] = Bb + (size_t)(bn + q * 64 + srow) * FEAT + sslot * 8;
    }
    const int ldsoff = tid * 16;

    f32x4 acc[8][4];
    #pragma unroll
    for (int i = 0; i < 8; ++i)
        #pragma unroll
        for (int j = 0; j < 4; ++j) { f32x4 z = {0.f, 0.f, 0.f, 0.f}; acc[i][j] = z; }

    #pragma unroll
    for (int q = 0; q < 4; ++q) {
        gload_lds16(gA[q], lds + q * 8192 + ldsoff);
        gload_lds16(gB[q], lds + 32768 + q * 8192 + ldsoff);
    }

    for (int t = 0; t < 32; ++t) {
        const int d = t & 1;
        const char* LA = lds + d * 65536;
        const char* LB = LA + 32768;
        char* SA = lds + (d ^ 1) * 65536;
        char* SB = SA + 32768;
        const int knext = (t + 1) * 64;

        asm volatile("s_waitcnt vmcnt(0)" ::: "memory");
        __builtin_amdgcn_s_barrier();

        #pragma unroll
        for (int kk = 0; kk < 2; ++kk) {
            const int kbyte = kk * 64 + fq * 16;
            s16x8 aF[8], bF[4];
            #pragma unroll
            for (int i = 0; i < 8; ++i) {
                const int row = wr * 128 + i * 16 + fr;
                aF[i] = *(const s16x8*)(LA + row * 128 + (kbyte ^ ((row & 7) << 4)));
            }
            #pragma unroll
            for (int j = 0; j < 4; ++j) {
                const int row = wc * 64 + j * 16 + fr;
                bF[j] = *(const s16x8*)(LB + row * 128 + (kbyte ^ ((row & 7) << 4)));
            }
            if (t < 31) {
                if (kk == 0) {
                    #pragma unroll
                    for (int q = 0; q < 4; ++q)
                        gload_lds16(gA[q] + knext, SA + q * 8192 + ldsoff);
                } else {
                    #pragma unroll
                    for (int q = 0; q < 4; ++q)
                        gload_lds16(gB[q] + knext, SB + q * 8192 + ldsoff);
                }
            }
            __builtin_amdgcn_s_setprio(1);
            #pragma unroll
            for (int i = 0; i < 8; ++i)
                #pragma unroll
                for (int j = 0; j < 4; ++j)
                    acc[i][j] = __builtin_amdgcn_mfma_f32_16x16x32_bf16(
                        aF[i], bF[j], acc[i][j], 0, 0, 0);
            __builtin_amdgcn_s_setprio(0);
        }
    }

    #pragma unroll
    for (int j = 0; j < 4; ++j) {
        const int col = bn + wc * 64 + j * 16 + fr;
        const float bias = bx[col] + bh[col];
        #pragma unroll
        for (int i = 0; i < 8; ++i) {
            const int rowb = bm + wr * 128 + i * 16 + fq * 4;
            #pragma unroll
            for (int reg = 0; reg < 4; ++reg)
                xproj[(size_t)(rowb + reg) * FH + col] =
                    __float2half_rn(acc[i][j][reg] + bias);
        }
    }
}

// ---------------------------------------------------------------------------
// Large levels (R9-proven): gather-free, BK=64, 2-buffer. Parents contiguous:
// node t = start + r has parent prevstart + (r>>1). B: tile row r -> Wh row
// ((r>>4)&3)*1024 + jg0 + (r>>6)*16 + (r&15) -> gates in-register.
// ---------------------------------------------------------------------------
template<int BM>
__global__ __launch_bounds__(512, 2) void level_kk(
    const __half* __restrict__ xproj, const unsigned short* __restrict__ Whb,
    int start, int prevstart, unsigned short* __restrict__ h_buf,
    float* __restrict__ c_buf, float* __restrict__ out)
{
    constexpr int MR = BM / 32;
    constexpr int ABYTES = BM * 128;
    constexpr int BUF = ABYTES + 32768;
    __shared__ char lds[2 * BUF];
    const int tid = threadIdx.x;
    const int wid = tid >> 6, lane = tid & 63;
    const int wr = wid >> 2, wc = wid & 3;
    const int fr = lane & 15, fq = lane >> 4;
    const int t0 = start + blockIdx.x * BM;
    const int jg0 = blockIdx.y * 64;

    const int srow = tid >> 3;
    const int sslot = (tid & 7) ^ (srow & 7);
    const unsigned short* gA[BM / 64];
    #pragma unroll
    for (int q = 0; q < BM / 64; ++q) {
        const int rg = blockIdx.x * BM + q * 64 + srow;
        gA[q] = h_buf + (size_t)(prevstart + (rg >> 1) + 1) * HD + sslot * 8;
    }
    const unsigned short* gB[4];
    #pragma unroll
    for (int q = 0; q < 4; ++q) {
        const int r = q * 64 + srow;
        const int whrow = ((r >> 4) & 3) * 1024 + jg0 + ((r >> 6) * 16) + (r & 15);
        gB[q] = Whb + (size_t)whrow * HD + sslot * 8;
    }
    const int ldsoff = tid * 16;

    f32x4 acc[MR][4];
    #pragma unroll
    for (int i = 0; i < MR; ++i)
        #pragma unroll
        for (int j = 0; j < 4; ++j) { f32x4 z = {0.f, 0.f, 0.f, 0.f}; acc[i][j] = z; }

    #pragma unroll
    for (int q = 0; q < BM / 64; ++q)
        gload_lds16(gA[q], lds + q * 8192 + ldsoff);
    #pragma unroll
    for (int q = 0; q < 4; ++q)
        gload_lds16(gB[q], lds + ABYTES + q * 8192 + ldsoff);

    for (int t = 0; t < 16; ++t) {
        const char* LA = lds + (t & 1) * BUF;
        const char* LB = LA + ABYTES;
        char* SA = lds + ((t & 1) ^ 1) * BUF;
        char* SB = SA + ABYTES;
        const int knext = (t + 1) * 64;

        asm volatile("s_waitcnt vmcnt(0)" ::: "memory");
        __builtin_amdgcn_s_barrier();

        #pragma unroll
        for (int kk = 0; kk < 2; ++kk) {
            const int kbyte = kk * 64 + fq * 16;
            s16x8 aF[MR], bF[4];
            #pragma unroll
            for (int i = 0; i < MR; ++i) {
                const int row = wr * (BM / 2) + i * 16 + fr;
                aF[i] = *(const s16x8*)(LA + row * 128 + (kbyte ^ ((row & 7) << 4)));
            }
            #pragma unroll
            for (int j = 0; j < 4; ++j) {
                const int row = wc * 64 + j * 16 + fr;
                bF[j] = *(const s16x8*)(LB + row * 128 + (kbyte ^ ((row & 7) << 4)));
            }
            if (t < 15) {
                if (kk == 0) {
                    #pragma unroll
                    for (int q = 0; q < BM / 64; ++q)
                        gload_lds16(gA[q] + knext, SA + q * 8192 + ldsoff);
                } else {
                    #pragma unroll
                    for (int q = 0; q < 4; ++q)
                        gload_lds16(gB[q] + knext, SB + q * 8192 + ldsoff);
                }
            }
            __builtin_amdgcn_s_setprio(1);
            #pragma unroll
            for (int i = 0; i < MR; ++i)
                #pragma unroll
                for (int j = 0; j < 4; ++j)
                    acc[i][j] = __builtin_amdgcn_mfma_f32_16x16x32_bf16(
                        aF[i], bF[j], acc[i][j], 0, 0, 0);
            __builtin_amdgcn_s_setprio(0);
        }
    }

    const int col = jg0 + wc * 16 + fr;
    #pragma unroll
    for (int i = 0; i < MR; ++i) {
        #pragma unroll
        for (int reg = 0; reg < 4; ++reg) {
            const int t = t0 + wr * (BM / 2) + i * 16 + fq * 4 + reg;
            const int p = (t - 1) >> 1;
            const size_t xb = (size_t)t * FH + col;
            const float gi = acc[i][0][reg] + __half2float(xproj[xb]);
            const float go = acc[i][1][reg] + __half2float(xproj[xb + HD]);
            const float gf = acc[i][2][reg] + __half2float(xproj[xb + 2 * HD]);
            const float gu = acc[i][3][reg] + __half2float(xproj[xb + 3 * HD]);
            const float cp = c_buf[(size_t)(p + 1) * HD + col];
            const float c = fast_sig(gi) * fast_tanh(gu) + fast_sig(gf) * cp;
            const float h = fast_sig(go) * fast_tanh(c);
            c_buf[(size_t)(t + 1) * HD + col] = c;
            h_buf[(size_t)(t + 1) * HD + col] = f2bf(h);
            out[(size_t)t * HD + col] = h;
        }
    }
}

// ---------------------------------------------------------------------------
// Shared gate epilogue (small levels, parent[] gather path)
// ---------------------------------------------------------------------------
__device__ __forceinline__ void level_epilogue(
    f32x4 (&acc)[4][4], const __half* __restrict__ xproj,
    const int* __restrict__ parent, unsigned short* __restrict__ h_buf,
    float* __restrict__ c_buf, float* __restrict__ out,
    int t0, int lim, int wm, int col, int fq)
{
    #pragma unroll
    for (int i = 0; i < 4; ++i) {
        #pragma unroll
        for (int reg = 0; reg < 4; ++reg) {
            const int t = t0 + wm + i * 16 + fq * 4 + reg;
            if (t < lim) {
                const int p = parent[t];
                const size_t xb = (size_t)t * FH + col;
                const float gi = acc[i][0][reg] + __half2float(xproj[xb]);
                const float go = acc[i][1][reg] + __half2float(xproj[xb + HD]);
                const float gf = acc[i][2][reg] + __half2float(xproj[xb + 2 * HD]);
                const float gu = acc[i][3][reg] + __half2float(xproj[xb + 3 * HD]);
                const float cp = c_buf[(size_t)(p + 1) * HD + col];
                const float c = fast_sig(gi) * fast_tanh(gu) + fast_sig(gf) * cp;
                const float h = fast_sig(go) * fast_tanh(c);
                c_buf[(size_t)(t + 1) * HD + col] = c;
                h_buf[(size_t)(t + 1) * HD + col] = f2bf(h);
                out[(size_t)t * HD + col] = h;
            }
        }
    }
}

// ---------------------------------------------------------------------------
// BK=128 helpers (small levels)
// ---------------------------------------------------------------------------
__device__ __forceinline__ void bk128_issue(
    const unsigned short* const (&gA)[8], const unsigned short* const (&gB)[8],
    int k0, unsigned short* As, unsigned short* Bs, int wbase)
{
    #pragma unroll
    for (int q = 0; q < 8; ++q) {
        gload_lds16(gA[q] + k0, (char*)As + q * 4096 + wbase);
        gload_lds16(gB[q] + k0, (char*)Bs + q * 4096 + wbase);
    }
}

__device__ __forceinline__ void bk128_compute(
    const unsigned short* As, const unsigned short* Bs,
    f32x4 (&acc)[4][4], int wm, int wn16, int fr, int fkb)
{
    #pragma unroll
    for (int kk = 0; kk < 4; ++kk) {
        s16x8 aF[4], bF[4];
        #pragma unroll
        for (int i = 0; i < 4; ++i) {
            const int r = wm + i * 16 + fr;
            const int byteIn = (kk * 64 + fkb) ^ ((r & 7) << 4);
            aF[i] = *(const s16x8*)((const char*)As + r * 256 + byteIn);
        }
        #pragma unroll
        for (int g = 0; g < 4; ++g) {
            const int r = g * 32 + wn16 + fr;
            const int byteIn = (kk * 64 + fkb) ^ ((r & 7) << 4);
            bF[g] = *(const s16x8*)((const char*)Bs + r * 256 + byteIn);
        }
        #pragma unroll
        for (int i = 0; i < 4; ++i)
            #pragma unroll
            for (int g = 0; g < 4; ++g)
                acc[i][g] = __builtin_amdgcn_mfma_f32_16x16x32_bf16(aF[i], bF[g], acc[i][g], 0, 0, 0);
    }
}

// ---------------------------------------------------------------------------
// Small levels (count <= 512): BK=128 double-buffered (R5-proven)
// ---------------------------------------------------------------------------
__global__ __launch_bounds__(256) void level_bk128_dbuf(
    const __half* __restrict__ xproj, const unsigned short* __restrict__ Whb,
    const int* __restrict__ parent, unsigned short* __restrict__ h_buf,
    float* __restrict__ c_buf, float* __restrict__ out,
    int start, int count)
{
    __shared__ unsigned short As0[128 * 128];
    __shared__ unsigned short Bs0[128 * 128];
    __shared__ unsigned short As1[128 * 128];
    __shared__ unsigned short Bs1[128 * 128];
    const int tid = threadIdx.x;
    const int wid = tid >> 6;
    const int lane = tid & 63;
    const int t0 = start + blockIdx.x * 128;
    const int jg0 = blockIdx.y * 32;
    const int lim = start + count;
    const int wm = (wid & 1) * 64;
    const int wn16 = (wid >> 1) * 16;
    const int wbase = wid * 1024;
    const int srow_b = tid >> 4;
    const int rowbyte = (tid & 15) * 16;

    const unsigned short* gA[8];
    const unsigned short* gB[8];
    #pragma unroll
    for (int q = 0; q < 8; ++q) {
        const int r = q * 16 + srow_b;
        const int sk = (rowbyte ^ ((r & 7) << 4)) >> 1;
        const int tA = min(t0 + r, lim - 1);
        gA[q] = h_buf + (size_t)(parent[tA] + 1) * HD + sk;
        const int whrow = ((r >> 5) << 10) + jg0 + (r & 31);
        gB[q] = Whb + (size_t)whrow * HD + sk;
    }

    f32x4 acc[4][4];
    #pragma unroll
    for (int i = 0; i < 4; ++i)
        #pragma unroll
        for (int g = 0; g < 4; ++g) { f32x4 z = {0.f, 0.f, 0.f, 0.f}; acc[i][g] = z; }

    const int fr = lane & 15;
    const int fkb = (lane >> 4) * 16;

    bk128_issue(gA, gB, 0, As0, Bs0, wbase);
    #pragma unroll
    for (int t = 0; t < 8; ++t) {
        unsigned short* curA = (t & 1) ? As1 : As0;
        unsigned short* curB = (t & 1) ? Bs1 : Bs0;
        unsigned short* nxtA = (t & 1) ? As0 : As1;
        unsigned short* nxtB = (t & 1) ? Bs0 : Bs1;
        if (t < 7) {
            bk128_issue(gA, gB, (t + 1) * 128, nxtA, nxtB, wbase);
            asm volatile("s_waitcnt vmcnt(16)" ::: "memory");
        } else {
            asm volatile("s_waitcnt vmcnt(0)" ::: "memory");
        }
        __builtin_amdgcn_s_barrier();
        __builtin_amdgcn_sched_barrier(0);
        bk128_compute(curA, curB, acc, wm, wn16, fr, fkb);
        __builtin_amdgcn_sched_barrier(0);
        __builtin_amdgcn_s_barrier();
    }

    level_epilogue(acc, xproj, parent, h_buf, c_buf, out,
                   t0, lim, wm, jg0 + wn16 + fr, lane >> 4);
}

extern "C" void kernel_launch(void* const* d_in, const int* in_sizes, int n_in,
                              void* d_out, int out_size, void* d_ws, size_t ws_size,
                              hipStream_t stream) {
    const float* feat   = (const float*)d_in[0];
    const float* Wx     = (const float*)d_in[1];
    const float* bx     = (const float*)d_in[2];
    const float* Wh     = (const float*)d_in[3];
    const float* bh     = (const float*)d_in[4];
    const int*   parent = (const int*)d_in[5];
    const float* root_c = (const float*)d_in[6];
    const float* root_h = (const float*)d_in[7];
    float* out = (float*)d_out;

    char* ws = (char*)d_ws;
    __half* xproj = (__half*)ws;                        ws += (size_t)NN * FH * 2;
    float* c_buf = (float*)ws;                          ws += (size_t)(NN + 1) * HD * 4;
    unsigned short* feat_b = (unsigned short*)ws;       ws += (size_t)NN * FEAT * 2;
    unsigned short* Wx_b = (unsigned short*)ws;         ws += (size_t)FH * FEAT * 2;
    unsigned short* Wh_b = (unsigned short*)ws;         ws += (size_t)FH * HD * 2;
    unsigned short* h_buf = (unsigned short*)ws;        ws += (size_t)(NN + 1) * HD * 2;

    const size_t ntot = (size_t)NN * FEAT + (size_t)FH * FEAT + (size_t)FH * HD;
    convert_all_kernel<<<(unsigned)(ntot / 8 / 256), 256, 0, stream>>>(
        feat, Wx, Wh, feat_b, Wx_b, Wh_b, root_h, root_c, h_buf, c_buf);

    dim3 g1(NN / 256, FH / 256);
    xproj_8ph<<<g1, 512, 0, stream>>>(feat_b, Wx_b, bx, bh, xproj);

    // small levels (counts 1..512), gathered via parent[]
    for (int start = 0, sz = 1; sz <= 512; start += sz, sz *= 2) {
        dim3 g2((sz + 127) / 128, HD / 32);
        level_bk128_dbuf<<<g2, 256, 0, stream>>>(
            xproj, Wh_b, parent, h_buf, c_buf, out, start, sz);
    }

    // large levels: gather-free kk-split (R9-proven), 256 blocks each
    dim3 gl(16, 16);
    level_kk<64><<<gl, 512, 0, stream>>>(xproj, Wh_b, 1023, 511,
                                         h_buf, c_buf, out);
    level_kk<128><<<gl, 512, 0, stream>>>(xproj, Wh_b, 2047, 1023,
                                          h_buf, c_buf, out);
    level_kk<256><<<gl, 512, 0, stream>>>(xproj, Wh_b, 4095, 2047,
                                          h_buf, c_buf, out);

    // straggler node 8191 (parent 4095 via h_buf/c_buf)
    dim3 g3(1, HD / 32);
    level_bk128_dbuf<<<g3, 256, 0, stream>>>(
        xproj, Wh_b, parent, h_buf, c_buf, out, 8191, 1);
}

// Round 13
// 434.471 us; speedup vs baseline: 3.7368x; 1.0385x over previous
//
#include <hip/hip_runtime.h>
#include <hip/hip_fp16.h>
#include <math.h>

#define FEAT 2048
#define HD 1024
#define FH 4096
#define NN 8192

using s16x8 = __attribute__((ext_vector_type(8))) short;
using f32x4 = __attribute__((ext_vector_type(4))) float;

#define GLOBAL_AS __attribute__((address_space(1)))
#define LDS_AS __attribute__((address_space(3)))

__device__ __forceinline__ void gload_lds16(const void* g, void* l) {
    __builtin_amdgcn_global_load_lds((const GLOBAL_AS unsigned int*)g,
                                     (LDS_AS unsigned int*)l, 16, 0, 0);
}

__device__ __forceinline__ unsigned short f2bf(float f) {
    union { float f; unsigned u; } v; v.f = f;
    unsigned r = v.u + 0x7FFFu + ((v.u >> 16) & 1u);  // RNE
    return (unsigned short)(r >> 16);
}

__device__ __forceinline__ float fast_sig(float x) { return 1.0f / (1.0f + __expf(-x)); }
__device__ __forceinline__ float fast_tanh(float x) {
    float ax = fabsf(x);
    float e = __expf(2.0f * ax);
    float r = 1.0f - 2.0f / (e + 1.0f);
    return copysignf(r, x);
}

// ---------------------------------------------------------------------------
// fused fp32 -> bf16 convert for feat, Wx, Wh  (+ root h/c init, fused)
// ---------------------------------------------------------------------------
__global__ __launch_bounds__(256) void convert_all_kernel(
    const float* __restrict__ feat, const float* __restrict__ Wx,
    const float* __restrict__ Wh, unsigned short* __restrict__ feat_b,
    unsigned short* __restrict__ Wx_b, unsigned short* __restrict__ Wh_b,
    const float* __restrict__ root_h, const float* __restrict__ root_c,
    unsigned short* __restrict__ h_buf, float* __restrict__ c_buf)
{
    const size_t g = (size_t)blockIdx.x * 256 + threadIdx.x;
    if (g < HD) { h_buf[g] = f2bf(root_h[g]); c_buf[g] = root_c[g]; }

    const size_t n1 = (size_t)NN * FEAT;
    const size_t n2 = n1 + (size_t)FH * FEAT;
    size_t i = g * 8;
    const float* s; unsigned short* d;
    if (i < n1)      { s = feat + i;        d = feat_b + i; }
    else if (i < n2) { s = Wx + (i - n1);   d = Wx_b + (i - n1); }
    else             { s = Wh + (i - n2);   d = Wh_b + (i - n2); }
    float4 a = *(const float4*)s;
    float4 b = *(const float4*)(s + 4);
    unsigned short r[8] = {f2bf(a.x), f2bf(a.y), f2bf(a.z), f2bf(a.w),
                           f2bf(b.x), f2bf(b.y), f2bf(b.z), f2bf(b.w)};
    *(s16x8*)d = *(const s16x8*)r;
}

// ---------------------------------------------------------------------------
// xproj = feat @ Wx^T + (bx+bh). 256x256 BK=64 kk-split (R7-proven schedule).
// fp16 output, written via LDS repack: wave-private [128 rows][128 B] region
// with chunk-XOR (chunk ^= row&7), then 16 B/lane stores (128 B contiguous
// per row-group -> full HBM sectors; R12's direct 2-B stores were half-sector
// = zero write saving).
// ---------------------------------------------------------------------------
__global__ __launch_bounds__(512, 2) void xproj_8ph(
    const unsigned short* __restrict__ Ab,
    const unsigned short* __restrict__ Bb,
    const float* __restrict__ bx, const float* __restrict__ bh,
    __half* __restrict__ xproj)
{
    __shared__ char lds[131072];
    const int tid = threadIdx.x;
    const int wid = tid >> 6;
    const int lane = tid & 63;
    const int wr = wid >> 2;
    const int wc = wid & 3;
    const int bm = blockIdx.x * 256;
    const int bn = blockIdx.y * 256;
    const int fr = lane & 15;
    const int fq = lane >> 4;

    const int srow = tid >> 3;
    const int sslot = (tid & 7) ^ (srow & 7);
    const unsigned short* gA[4];
    const unsigned short* gB[4];
    #pragma unroll
    for (int q = 0; q < 4; ++q) {
        gA[q] = Ab + (size_t)(bm + q * 64 + srow) * FEAT + sslot * 8;
        gB[q] = Bb + (size_t)(bn + q * 64 + srow) * FEAT + sslot * 8;
    }
    const int ldsoff = tid * 16;

    f32x4 acc[8][4];
    #pragma unroll
    for (int i = 0; i < 8; ++i)
        #pragma unroll
        for (int j = 0; j < 4; ++j) { f32x4 z = {0.f, 0.f, 0.f, 0.f}; acc[i][j] = z; }

    #pragma unroll
    for (int q = 0; q < 4; ++q) {
        gload_lds16(gA[q], lds + q * 8192 + ldsoff);
        gload_lds16(gB[q], lds + 32768 + q * 8192 + ldsoff);
    }

    for (int t = 0; t < 32; ++t) {
        const int d = t & 1;
        const char* LA = lds + d * 65536;
        const char* LB = LA + 32768;
        char* SA = lds + (d ^ 1) * 65536;
        char* SB = SA + 32768;
        const int knext = (t + 1) * 64;

        asm volatile("s_waitcnt vmcnt(0)" ::: "memory");
        __builtin_amdgcn_s_barrier();

        #pragma unroll
        for (int kk = 0; kk < 2; ++kk) {
            const int kbyte = kk * 64 + fq * 16;
            s16x8 aF[8], bF[4];
            #pragma unroll
            for (int i = 0; i < 8; ++i) {
                const int row = wr * 128 + i * 16 + fr;
                aF[i] = *(const s16x8*)(LA + row * 128 + (kbyte ^ ((row & 7) << 4)));
            }
            #pragma unroll
            for (int j = 0; j < 4; ++j) {
                const int row = wc * 64 + j * 16 + fr;
                bF[j] = *(const s16x8*)(LB + row * 128 + (kbyte ^ ((row & 7) << 4)));
            }
            if (t < 31) {
                if (kk == 0) {
                    #pragma unroll
                    for (int q = 0; q < 4; ++q)
                        gload_lds16(gA[q] + knext, SA + q * 8192 + ldsoff);
                } else {
                    #pragma unroll
                    for (int q = 0; q < 4; ++q)
                        gload_lds16(gB[q] + knext, SB + q * 8192 + ldsoff);
                }
            }
            __builtin_amdgcn_s_setprio(1);
            #pragma unroll
            for (int i = 0; i < 8; ++i)
                #pragma unroll
                for (int j = 0; j < 4; ++j)
                    acc[i][j] = __builtin_amdgcn_mfma_f32_16x16x32_bf16(
                        aF[i], bF[j], acc[i][j], 0, 0, 0);
            __builtin_amdgcn_s_setprio(0);
        }
    }

    // ---- epilogue: LDS repack to coalesced fp16 stores ----
    __builtin_amdgcn_s_barrier();           // all waves done with K-loop LDS
    char* W = lds + wid * 16384;            // wave-private [128][128 B]
    #pragma unroll
    for (int j = 0; j < 4; ++j) {
        const int c_loc = j * 16 + fr;      // 0..63
        const int col = bn + wc * 64 + c_loc;
        const float bias = bx[col] + bh[col];
        #pragma unroll
        for (int i = 0; i < 8; ++i) {
            #pragma unroll
            for (int reg = 0; reg < 4; ++reg) {
                const int r_loc = i * 16 + fq * 4 + reg;   // 0..127
                const int byteo = r_loc * 128 +
                    ((((c_loc >> 3) ^ (r_loc & 7)) << 4)) + (c_loc & 7) * 2;
                *(__half*)(W + byteo) = __float2half_rn(acc[i][j][reg] + bias);
            }
        }
    }
    asm volatile("s_waitcnt lgkmcnt(0)" ::: "memory");   // wave-private: no barrier
    #pragma unroll
    for (int k = 0; k < 16; ++k) {
        const int f = k * 64 + lane;        // 0..1023 = 128 rows x 8 chunks
        const int r_loc = f >> 3;
        const int cchunk = f & 7;
        const s16x8 v = *(const s16x8*)(W + r_loc * 128 +
                                        ((cchunk ^ (r_loc & 7)) << 4));
        const int grow = bm + wr * 128 + r_loc;
        const int gcol = bn + wc * 64 + cchunk * 8;
        *(s16x8*)((unsigned short*)xproj + (size_t)grow * FH + gcol) = v;
    }
}

// ---------------------------------------------------------------------------
// Large levels (R9-proven): gather-free, BK=64, 2-buffer. Parents contiguous:
// node t = start + r has parent prevstart + (r>>1). B: tile row r -> Wh row
// ((r>>4)&3)*1024 + jg0 + (r>>6)*16 + (r&15) -> gates in-register.
// ---------------------------------------------------------------------------
template<int BM>
__global__ __launch_bounds__(512, 2) void level_kk(
    const __half* __restrict__ xproj, const unsigned short* __restrict__ Whb,
    int start, int prevstart, unsigned short* __restrict__ h_buf,
    float* __restrict__ c_buf, float* __restrict__ out)
{
    constexpr int MR = BM / 32;
    constexpr int ABYTES = BM * 128;
    constexpr int BUF = ABYTES + 32768;
    __shared__ char lds[2 * BUF];
    const int tid = threadIdx.x;
    const int wid = tid >> 6, lane = tid & 63;
    const int wr = wid >> 2, wc = wid & 3;
    const int fr = lane & 15, fq = lane >> 4;
    const int t0 = start + blockIdx.x * BM;
    const int jg0 = blockIdx.y * 64;

    const int srow = tid >> 3;
    const int sslot = (tid & 7) ^ (srow & 7);
    const unsigned short* gA[BM / 64];
    #pragma unroll
    for (int q = 0; q < BM / 64; ++q) {
        const int rg = blockIdx.x * BM + q * 64 + srow;
        gA[q] = h_buf + (size_t)(prevstart + (rg >> 1) + 1) * HD + sslot * 8;
    }
    const unsigned short* gB[4];
    #pragma unroll
    for (int q = 0; q < 4; ++q) {
        const int r = q * 64 + srow;
        const int whrow = ((r >> 4) & 3) * 1024 + jg0 + ((r >> 6) * 16) + (r & 15);
        gB[q] = Whb + (size_t)whrow * HD + sslot * 8;
    }
    const int ldsoff = tid * 16;

    f32x4 acc[MR][4];
    #pragma unroll
    for (int i = 0; i < MR; ++i)
        #pragma unroll
        for (int j = 0; j < 4; ++j) { f32x4 z = {0.f, 0.f, 0.f, 0.f}; acc[i][j] = z; }

    #pragma unroll
    for (int q = 0; q < BM / 64; ++q)
        gload_lds16(gA[q], lds + q * 8192 + ldsoff);
    #pragma unroll
    for (int q = 0; q < 4; ++q)
        gload_lds16(gB[q], lds + ABYTES + q * 8192 + ldsoff);

    for (int t = 0; t < 16; ++t) {
        const char* LA = lds + (t & 1) * BUF;
        const char* LB = LA + ABYTES;
        char* SA = lds + ((t & 1) ^ 1) * BUF;
        char* SB = SA + ABYTES;
        const int knext = (t + 1) * 64;

        asm volatile("s_waitcnt vmcnt(0)" ::: "memory");
        __builtin_amdgcn_s_barrier();

        #pragma unroll
        for (int kk = 0; kk < 2; ++kk) {
            const int kbyte = kk * 64 + fq * 16;
            s16x8 aF[MR], bF[4];
            #pragma unroll
            for (int i = 0; i < MR; ++i) {
                const int row = wr * (BM / 2) + i * 16 + fr;
                aF[i] = *(const s16x8*)(LA + row * 128 + (kbyte ^ ((row & 7) << 4)));
            }
            #pragma unroll
            for (int j = 0; j < 4; ++j) {
                const int row = wc * 64 + j * 16 + fr;
                bF[j] = *(const s16x8*)(LB + row * 128 + (kbyte ^ ((row & 7) << 4)));
            }
            if (t < 15) {
                if (kk == 0) {
                    #pragma unroll
                    for (int q = 0; q < BM / 64; ++q)
                        gload_lds16(gA[q] + knext, SA + q * 8192 + ldsoff);
                } else {
                    #pragma unroll
                    for (int q = 0; q < 4; ++q)
                        gload_lds16(gB[q] + knext, SB + q * 8192 + ldsoff);
                }
            }
            __builtin_amdgcn_s_setprio(1);
            #pragma unroll
            for (int i = 0; i < MR; ++i)
                #pragma unroll
                for (int j = 0; j < 4; ++j)
                    acc[i][j] = __builtin_amdgcn_mfma_f32_16x16x32_bf16(
                        aF[i], bF[j], acc[i][j], 0, 0, 0);
            __builtin_amdgcn_s_setprio(0);
        }
    }

    const int col = jg0 + wc * 16 + fr;
    #pragma unroll
    for (int i = 0; i < MR; ++i) {
        #pragma unroll
        for (int reg = 0; reg < 4; ++reg) {
            const int t = t0 + wr * (BM / 2) + i * 16 + fq * 4 + reg;
            const int p = (t - 1) >> 1;
            const size_t xb = (size_t)t * FH + col;
            const float gi = acc[i][0][reg] + __half2float(xproj[xb]);
            const float go = acc[i][1][reg] + __half2float(xproj[xb + HD]);
            const float gf = acc[i][2][reg] + __half2float(xproj[xb + 2 * HD]);
            const float gu = acc[i][3][reg] + __half2float(xproj[xb + 3 * HD]);
            const float cp = c_buf[(size_t)(p + 1) * HD + col];
            const float c = fast_sig(gi) * fast_tanh(gu) + fast_sig(gf) * cp;
            const float h = fast_sig(go) * fast_tanh(c);
            c_buf[(size_t)(t + 1) * HD + col] = c;
            h_buf[(size_t)(t + 1) * HD + col] = f2bf(h);
            out[(size_t)t * HD + col] = h;
        }
    }
}

// ---------------------------------------------------------------------------
// Shared gate epilogue (small levels, parent[] gather path)
// ---------------------------------------------------------------------------
__device__ __forceinline__ void level_epilogue(
    f32x4 (&acc)[4][4], const __half* __restrict__ xproj,
    const int* __restrict__ parent, unsigned short* __restrict__ h_buf,
    float* __restrict__ c_buf, float* __restrict__ out,
    int t0, int lim, int wm, int col, int fq)
{
    #pragma unroll
    for (int i = 0; i < 4; ++i) {
        #pragma unroll
        for (int reg = 0; reg < 4; ++reg) {
            const int t = t0 + wm + i * 16 + fq * 4 + reg;
            if (t < lim) {
                const int p = parent[t];
                const size_t xb = (size_t)t * FH + col;
                const float gi = acc[i][0][reg] + __half2float(xproj[xb]);
                const float go = acc[i][1][reg] + __half2float(xproj[xb + HD]);
                const float gf = acc[i][2][reg] + __half2float(xproj[xb + 2 * HD]);
                const float gu = acc[i][3][reg] + __half2float(xproj[xb + 3 * HD]);
                const float cp = c_buf[(size_t)(p + 1) * HD + col];
                const float c = fast_sig(gi) * fast_tanh(gu) + fast_sig(gf) * cp;
                const float h = fast_sig(go) * fast_tanh(c);
                c_buf[(size_t)(t + 1) * HD + col] = c;
                h_buf[(size_t)(t + 1) * HD + col] = f2bf(h);
                out[(size_t)t * HD + col] = h;
            }
        }
    }
}

// ---------------------------------------------------------------------------
// BK=128 helpers (small levels)
// ---------------------------------------------------------------------------
__device__ __forceinline__ void bk128_issue(
    const unsigned short* const (&gA)[8], const unsigned short* const (&gB)[8],
    int k0, unsigned short* As, unsigned short* Bs, int wbase)
{
    #pragma unroll
    for (int q = 0; q < 8; ++q) {
        gload_lds16(gA[q] + k0, (char*)As + q * 4096 + wbase);
        gload_lds16(gB[q] + k0, (char*)Bs + q * 4096 + wbase);
    }
}

__device__ __forceinline__ void bk128_compute(
    const unsigned short* As, const unsigned short* Bs,
    f32x4 (&acc)[4][4], int wm, int wn16, int fr, int fkb)
{
    #pragma unroll
    for (int kk = 0; kk < 4; ++kk) {
        s16x8 aF[4], bF[4];
        #pragma unroll
        for (int i = 0; i < 4; ++i) {
            const int r = wm + i * 16 + fr;
            const int byteIn = (kk * 64 + fkb) ^ ((r & 7) << 4);
            aF[i] = *(const s16x8*)((const char*)As + r * 256 + byteIn);
        }
        #pragma unroll
        for (int g = 0; g < 4; ++g) {
            const int r = g * 32 + wn16 + fr;
            const int byteIn = (kk * 64 + fkb) ^ ((r & 7) << 4);
            bF[g] = *(const s16x8*)((const char*)Bs + r * 256 + byteIn);
        }
        #pragma unroll
        for (int i = 0; i < 4; ++i)
            #pragma unroll
            for (int g = 0; g < 4; ++g)
                acc[i][g] = __builtin_amdgcn_mfma_f32_16x16x32_bf16(aF[i], bF[g], acc[i][g], 0, 0, 0);
    }
}

// ---------------------------------------------------------------------------
// Small levels (count <= 512): BK=128 double-buffered (R5-proven)
// ---------------------------------------------------------------------------
__global__ __launch_bounds__(256) void level_bk128_dbuf(
    const __half* __restrict__ xproj, const unsigned short* __restrict__ Whb,
    const int* __restrict__ parent, unsigned short* __restrict__ h_buf,
    float* __restrict__ c_buf, float* __restrict__ out,
    int start, int count)
{
    __shared__ unsigned short As0[128 * 128];
    __shared__ unsigned short Bs0[128 * 128];
    __shared__ unsigned short As1[128 * 128];
    __shared__ unsigned short Bs1[128 * 128];
    const int tid = threadIdx.x;
    const int wid = tid >> 6;
    const int lane = tid & 63;
    const int t0 = start + blockIdx.x * 128;
    const int jg0 = blockIdx.y * 32;
    const int lim = start + count;
    const int wm = (wid & 1) * 64;
    const int wn16 = (wid >> 1) * 16;
    const int wbase = wid * 1024;
    const int srow_b = tid >> 4;
    const int rowbyte = (tid & 15) * 16;

    const unsigned short* gA[8];
    const unsigned short* gB[8];
    #pragma unroll
    for (int q = 0; q < 8; ++q) {
        const int r = q * 16 + srow_b;
        const int sk = (rowbyte ^ ((r & 7) << 4)) >> 1;
        const int tA = min(t0 + r, lim - 1);
        gA[q] = h_buf + (size_t)(parent[tA] + 1) * HD + sk;
        const int whrow = ((r >> 5) << 10) + jg0 + (r & 31);
        gB[q] = Whb + (size_t)whrow * HD + sk;
    }

    f32x4 acc[4][4];
    #pragma unroll
    for (int i = 0; i < 4; ++i)
        #pragma unroll
        for (int g = 0; g < 4; ++g) { f32x4 z = {0.f, 0.f, 0.f, 0.f}; acc[i][g] = z; }

    const int fr = lane & 15;
    const int fkb = (lane >> 4) * 16;

    bk128_issue(gA, gB, 0, As0, Bs0, wbase);
    #pragma unroll
    for (int t = 0; t < 8; ++t) {
        unsigned short* curA = (t & 1) ? As1 : As0;
        unsigned short* curB = (t & 1) ? Bs1 : Bs0;
        unsigned short* nxtA = (t & 1) ? As0 : As1;
        unsigned short* nxtB = (t & 1) ? Bs0 : Bs1;
        if (t < 7) {
            bk128_issue(gA, gB, (t + 1) * 128, nxtA, nxtB, wbase);
            asm volatile("s_waitcnt vmcnt(16)" ::: "memory");
        } else {
            asm volatile("s_waitcnt vmcnt(0)" ::: "memory");
        }
        __builtin_amdgcn_s_barrier();
        __builtin_amdgcn_sched_barrier(0);
        bk128_compute(curA, curB, acc, wm, wn16, fr, fkb);
        __builtin_amdgcn_sched_barrier(0);
        __builtin_amdgcn_s_barrier();
    }

    level_epilogue(acc, xproj, parent, h_buf, c_buf, out,
                   t0, lim, wm, jg0 + wn16 + fr, lane >> 4);
}

extern "C" void kernel_launch(void* const* d_in, const int* in_sizes, int n_in,
                              void* d_out, int out_size, void* d_ws, size_t ws_size,
                              hipStream_t stream) {
    const float* feat   = (const float*)d_in[0];
    const float* Wx     = (const float*)d_in[1];
    const float* bx     = (const float*)d_in[2];
    const float* Wh     = (const float*)d_in[3];
    const float* bh     = (const float*)d_in[4];
    const int*   parent = (const int*)d_in[5];
    const float* root_c = (const float*)d_in[6];
    const float* root_h = (const float*)d_in[7];
    float* out = (float*)d_out;

    char* ws = (char*)d_ws;
    __half* xproj = (__half*)ws;                        ws += (size_t)NN * FH * 2;
    float* c_buf = (float*)ws;                          ws += (size_t)(NN + 1) * HD * 4;
    unsigned short* feat_b = (unsigned short*)ws;       ws += (size_t)NN * FEAT * 2;
    unsigned short* Wx_b = (unsigned short*)ws;         ws += (size_t)FH * FEAT * 2;
    unsigned short* Wh_b = (unsigned short*)ws;         ws += (size_t)FH * HD * 2;
    unsigned short* h_buf = (unsigned short*)ws;        ws += (size_t)(NN + 1) * HD * 2;

    const size_t ntot = (size_t)NN * FEAT + (size_t)FH * FEAT + (size_t)FH * HD;
    convert_all_kernel<<<(unsigned)(ntot / 8 / 256), 256, 0, stream>>>(
        feat, Wx, Wh, feat_b, Wx_b, Wh_b, root_h, root_c, h_buf, c_buf);

    dim3 g1(NN / 256, FH / 256);
    xproj_8ph<<<g1, 512, 0, stream>>>(feat_b, Wx_b, bx, bh, xproj);

    // small levels (counts 1..512), gathered via parent[]
    for (int start = 0, sz = 1; sz <= 512; start += sz, sz *= 2) {
        dim3 g2((sz + 127) / 128, HD / 32);
        level_bk128_dbuf<<<g2, 256, 0, stream>>>(
            xproj, Wh_b, parent, h_buf, c_buf, out, start, sz);
    }

    // large levels: gather-free kk-split (R9-proven), 256 blocks each
    dim3 gl(16, 16);
    level_kk<64><<<gl, 512, 0, stream>>>(xproj, Wh_b, 1023, 511,
                                         h_buf, c_buf, out);
    level_kk<128><<<gl, 512, 0, stream>>>(xproj, Wh_b, 2047, 1023,
                                          h_buf, c_buf, out);
    level_kk<256><<<gl, 512, 0, stream>>>(xproj, Wh_b, 4095, 2047,
                                          h_buf, c_buf, out);

    // straggler node 8191 (parent 4095 via h_buf/c_buf)
    dim3 g3(1, HD / 32);
    level_bk128_dbuf<<<g3, 256, 0, stream>>>(
        xproj, Wh_b, parent, h_buf, c_buf, out, 8191, 1);
}